// Round 4
// baseline (141.440 us; speedup 1.0000x reference)
//
#include <hip/hip_runtime.h>
#include <stdint.h>

#define N_UNITS   400
#define N_NEIGHB  64
#define C         3
#define S         2
#define T         10      // C + C*S + E, E=1
#define NSLICE    256     // kA blocks / PA slabs
#define HW_       (N_NEIGHB * N_UNITS / 2)   // 12800 packed words (4 u8 fields each)
#define BS        256
#define BSA       1024                        // kA block size (4 waves/SIMD)
#define MCHUNK    2048                        // spikes per k_main block (8 tiles)
#define EHW       (N_UNITS * 16)              // 6400 u8x4-packed explore words

// ---------- JAX Threefry-2x32, key = (0, 1) (jax.random.key(1)) ----------
__device__ __forceinline__ uint32_t rotl32(uint32_t x, int d) {
    return (x << d) | (x >> (32 - d));
}

__device__ __forceinline__ void threefry_key01(uint32_t x0, uint32_t x1,
                                               uint32_t& o0, uint32_t& o1) {
    const uint32_t ks0 = 0u;
    const uint32_t ks1 = 1u;
    const uint32_t ks2 = 0x1BD11BDBu;  // 0x1BD11BDA ^ 0 ^ 1
    x0 += ks0; x1 += ks1;
#define TF_RND(r) { x0 += x1; x1 = rotl32(x1, r); x1 ^= x0; }
    TF_RND(13) TF_RND(15) TF_RND(26) TF_RND(6)
    x0 += ks1; x1 += ks2 + 1u;
    TF_RND(17) TF_RND(29) TF_RND(16) TF_RND(24)
    x0 += ks2; x1 += ks0 + 2u;
    TF_RND(13) TF_RND(15) TF_RND(26) TF_RND(6)
    x0 += ks0; x1 += ks1 + 3u;
    TF_RND(17) TF_RND(29) TF_RND(16) TF_RND(24)
    x0 += ks1; x1 += ks2 + 4u;
    TF_RND(13) TF_RND(15) TF_RND(26) TF_RND(6)
    x0 += ks2; x1 += ks0 + 5u;
#undef TF_RND
    o0 = x0; o1 = x1;
}

// jax_threefry_partitionable=True (default since jax 0.4.36):
// bits[i] = x0 ^ x1 of threefry2x32(key, (i >> 32, i & 0xffffffff)).
__device__ __forceinline__ int explore_index(int i, int ne) {
    uint32_t o0, o1;
    threefry_key01(0u, (uint32_t)i, o0, o1);
    uint32_t bits = o0 ^ o1;
    float u = __uint_as_float((bits >> 9) | 0x3F800000u) - 1.0f;
    int t = (int)floorf(u * (float)ne);
    return min(t, ne - 1);
}

// ---------- kA: single-pass full-64-nb partial histograms (u8 fields) -----
// entry e = nb*400+u; word = e>>1; lo/hi 16b half per e; within a half:
// bits 0-7 = h0 (top0 count), bits 8-15 = h12 (top1+top2 count).
// Per-slab counts are tiny (lambda ~0.3), so u8 cannot overflow.
// 1024 threads/block: 4 waves/SIMD.
__global__ void k_histA(const int* __restrict__ top,
                        const int* __restrict__ nbid,
                        uint32_t* __restrict__ PA, int n, int chunk) {
    __shared__ uint32_t hist[HW_];
    for (int k = threadIdx.x; k < HW_; k += blockDim.x) hist[k] = 0u;
    __syncthreads();
    int lo = blockIdx.x * chunk, hi = min(n, lo + chunk);
    const int4* top4 = (const int4*)top;
#define PROC(nb, t0, t1, t2) { \
    int b_ = (nb) * N_UNITS; \
    int e0 = b_ + (t0), e1 = b_ + (t1), e2 = b_ + (t2); \
    atomicAdd(&hist[e0 >> 1], 1u << ((e0 & 1) * 16)); \
    atomicAdd(&hist[e1 >> 1], 0x100u << ((e1 & 1) * 16)); \
    atomicAdd(&hist[e2 >> 1], 0x100u << ((e2 & 1) * 16)); }
    for (int i0 = lo + threadIdx.x * 4; i0 < hi; i0 += blockDim.x * 4) {
        if (i0 + 4 <= hi) {
            int4 nb4 = *(const int4*)(nbid + i0);
            int j = (i0 * 3) >> 2;
            int4 ta = top4[j], tb = top4[j + 1], tc = top4[j + 2];
            PROC(nb4.x, ta.x, ta.y, ta.z)
            PROC(nb4.y, ta.w, tb.x, tb.y)
            PROC(nb4.z, tb.z, tb.w, tc.x)
            PROC(nb4.w, tc.y, tc.z, tc.w)
        } else {
            for (int i = i0; i < hi; ++i)
                PROC(nbid[i], top[3 * i], top[3 * i + 1], top[3 * i + 2])
        }
    }
#undef PROC
    __syncthreads();
    uint32_t* Pb = PA + (size_t)blockIdx.x * HW_;
    for (int k = threadIdx.x; k < HW_; k += blockDim.x) Pb[k] = hist[k];
}

// ---------- kB (fused kR+kB): full slab reduce + tables + base counts -----
// One block per neighborhood; thread u sums its (nb,u) u8 fields across all
// 256 PA slabs (widened before accumulate), then ballot-scan tables.
__global__ void k_tables(const uint32_t* __restrict__ PA,
                         const int* __restrict__ usn,
                         int* __restrict__ wtbl,
                         int* __restrict__ wne,
                         float* __restrict__ out_counts) {
    __shared__ int s_c[N_UNITS];
    __shared__ int wsum[8];
    int b = blockIdx.x;          // neighborhood id
    int u = threadIdx.x;         // 512 threads = 8 waves
    int h0 = 0, h3 = 0;
    if (u < N_UNITS) {
        int w = b * (N_UNITS / 2) + (u >> 1);
        int sh = (u & 1) * 16;
        int a0 = 0, a12 = 0;
        const uint32_t* p = PA + w;
#pragma unroll 8
        for (int s = 0; s < NSLICE; ++s) {
            uint32_t v = p[(size_t)s * HW_] >> sh;
            a0  += (int)(v & 0xFFu);
            a12 += (int)((v >> 8) & 0xFFu);
        }
        h0 = a0;
        h3 = a0 + a12;
        s_c[u] = h3;              // top0 + top1/top2 contributions
    }
    bool pr = (u < N_UNITS) && (h0 > 0);
    unsigned long long m = __ballot(pr);
    int lane = u & 63, wid = u >> 6;
    if (lane == 0) wsum[wid] = __popcll(m);
    int lp = __popcll(m & ((1ull << lane) - 1ull));
    __syncthreads();              // covers s_c and wsum
    int off = 0;
    for (int w2 = 0; w2 < wid; ++w2) off += wsum[w2];
    if (pr) wtbl[b * N_UNITS + off + lp] = u;   // ascending unit order kept
    if (u == 0) {
        int tot = 0;
        for (int w2 = 0; w2 < 8; ++w2) tot += wsum[w2];
        wne[b] = tot;
    }
    if (u < N_UNITS && h3 > 0) {
        int2 nbr = ((const int2*)usn)[u];
        atomicAdd(&s_c[nbr.x], h3);
        atomicAdd(&s_c[nbr.y], h3);
    }
    __syncthreads();
    if (u < N_UNITS)
        out_counts[u * N_NEIGHB + b] = (float)s_c[u];
}

// ---------- k_main: pipelined candidates + scores + explore LDS hist ------
// Per 256-spike tile t (parity p = t&1):
//   A: stage s_top[p]  ->  barrier  ->  B: dump tile t-1 (buffer 1-p), then
//   compute tile t into s_bc[p].
// One barrier per tile; dump's global stores drain under the next tile's
// compute instead of at an immediate vmcnt(0) barrier.
__global__ void k_main(const float* __restrict__ logliks,
                       const int* __restrict__ top,
                       const int* __restrict__ usn,
                       const int* __restrict__ nbid,
                       const int* __restrict__ wtbl,
                       const int* __restrict__ wne,
                       uint32_t* __restrict__ PD,
                       float* __restrict__ out_cand,
                       float* __restrict__ out_scores,
                       int n, int chunk) {
    __shared__ uint32_t hist[EHW];
    __shared__ int   s_usn[N_UNITS * S];
    __shared__ float s_ll[N_UNITS];
    __shared__ int   s_ne[N_NEIGHB];
    __shared__ int   s_top[2][BS * 3];
    __shared__ float s_bc[2][BS * T];
    int tid = threadIdx.x;
    for (int k = tid; k < EHW; k += BS) hist[k] = 0u;
    for (int k = tid; k < N_UNITS * S; k += BS) s_usn[k] = usn[k];
    for (int k = tid; k < N_UNITS; k += BS)     s_ll[k]  = logliks[k];
    for (int k = tid; k < N_NEIGHB; k += BS)    s_ne[k]  = wne[k];
    __syncthreads();

    int lo = blockIdx.x * chunk, hi = min(n, lo + chunk);

    // dense coalesced dump of one staged tile; scores gathered from s_ll
    auto dump = [&](int t0d, int cntd, int q) {
        int nfloat = cntd * T;
        float* oc = out_cand   + (size_t)t0d * T;
        float* os = out_scores + (size_t)t0d * T;
        int nvec = nfloat & ~3;
        const float* bc = s_bc[q];
        for (int e = tid * 4; e < nvec; e += BS * 4) {
            float4 v = *(const float4*)(bc + e);
            *(float4*)(oc + e) = v;
            float4 sc;
            int i0 = (int)v.x, i1 = (int)v.y, i2 = (int)v.z, i3 = (int)v.w;
            sc.x = (i0 >= 0) ? s_ll[i0] : 0.0f;
            sc.y = (i1 >= 0) ? s_ll[i1] : 0.0f;
            sc.z = (i2 >= 0) ? s_ll[i2] : 0.0f;
            sc.w = (i3 >= 0) ? s_ll[i3] : 0.0f;
            *(float4*)(os + e) = sc;
        }
        for (int e = nvec + tid; e < nfloat; e += BS) {
            float v = bc[e];
            oc[e] = v;
            int iv = (int)v;
            os[e] = (iv >= 0) ? s_ll[iv] : 0.0f;
        }
    };

    int prev_t0 = -1, prev_cnt = 0, prev_p = 0;
    int tile = 0;
    for (int t0 = lo; t0 < hi; t0 += BS, ++tile) {
        int p = tile & 1;
        int cnt = min(BS, hi - t0);
        // A: stage this tile's top rows (t0 is 256-aligned -> int4-safe)
        if (cnt == BS) {
            if (tid < (BS * 3) / 4)
                ((int4*)s_top[p])[tid] = ((const int4*)(top + (size_t)t0 * 3))[tid];
        } else {
            for (int k = tid; k < cnt * 3; k += BS)
                s_top[p][k] = top[(size_t)t0 * 3 + k];
        }
        __syncthreads();   // s_top[p] ready; prev compute done; 2-old dump done

        // B1: dump previous tile (stores overlap the compute below)
        if (prev_t0 >= 0) dump(prev_t0, prev_cnt, prev_p);

        // B2: compute current tile into s_bc[p]
        int i = t0 + tid;
        if (i < hi) {
            int nb = nbid[i];
            int cand[T];
            cand[0] = s_top[p][tid * 3 + 0];
            cand[1] = s_top[p][tid * 3 + 1];
            cand[2] = s_top[p][tid * 3 + 2];
#pragma unroll
            for (int c = 0; c < C; ++c) {
                cand[C + 2 * c]     = s_usn[cand[c] * 2 + 0];
                cand[C + 2 * c + 1] = s_usn[cand[c] * 2 + 1];
            }
            int ne = s_ne[nb];
            if (ne > 0) {
                int t = explore_index(i, ne);
                int ex = wtbl[nb * N_UNITS + t];
                cand[T - 1] = ex;
                // explore tail-count (pre-dup), u8 field per nb
                atomicAdd(&hist[ex * 16 + (nb >> 2)], 1u << ((nb & 3) * 8));
            } else {
                cand[T - 1] = -1;
            }
#pragma unroll
            for (int jj = 0; jj < T; ++jj) {
                bool dup = false;
#pragma unroll
                for (int k = 0; k < jj; ++k) dup |= (cand[k] == cand[jj]);
                s_bc[p][tid * T + jj] = (float)(dup ? -1 : cand[jj]);
            }
        }
        prev_t0 = t0; prev_cnt = cnt; prev_p = p;
    }
    __syncthreads();        // last tile's s_bc writes complete
    if (prev_t0 >= 0) dump(prev_t0, prev_cnt, prev_p);

    // hist atomics all complete at the barrier above
    uint32_t* Pb = PD + (size_t)blockIdx.x * EHW;
    for (int k = tid; k < EHW; k += BS) Pb[k] = hist[k];
}

// ---------- kF: reduce u8-packed explore partials into out_counts ---------
// 200 blocks: 32 words x 8 slab-groups each.
__global__ void k_finalE(const uint32_t* __restrict__ PD,
                         float* __restrict__ out_counts, int nslab) {
    __shared__ uint32_t red_e[256], red_o[256];
    int tid = threadIdx.x;
    int wl = tid & 31, g = tid >> 5;            // 8 slab groups
    int w = blockIdx.x * 32 + wl;               // word index in [0, EHW)
    int per = (nslab + 7) >> 3;
    int s0 = g * per, s1 = min(nslab, s0 + per);
    uint32_t acc_e = 0, acc_o = 0;              // u16 lanes: fields 0/2, 1/3
    for (int s = s0; s < s1; ++s) {
        uint32_t v = PD[(size_t)s * EHW + w];
        acc_e += v & 0x00FF00FFu;
        acc_o += (v >> 8) & 0x00FF00FFu;
    }
    red_e[tid] = acc_e;
    red_o[tid] = acc_o;
    __syncthreads();
    if (g == 0) {
        // unpack BEFORE combining groups (avoid u16-lane carry)
        uint32_t c0 = 0, c1 = 0, c2 = 0, c3 = 0;
#pragma unroll
        for (int k = 0; k < 8; ++k) {
            uint32_t e = red_e[wl + 32 * k], o = red_o[wl + 32 * k];
            c0 += e & 0xFFFFu;  c2 += e >> 16;
            c1 += o & 0xFFFFu;  c3 += o >> 16;
        }
        int u = w >> 4, nb4 = (w & 15) * 4;
        float4* p = (float4*)(out_counts + u * N_NEIGHB + nb4);
        float4 v = *p;
        v.x += (float)c0;
        v.y += (float)c1;
        v.z += (float)c2;
        v.w += (float)c3;
        *p = v;
    }
}

extern "C" void kernel_launch(void* const* d_in, const int* in_sizes, int n_in,
                              void* d_out, int out_size, void* d_ws, size_t ws_size,
                              hipStream_t stream) {
    const float* logliks = (const float*)d_in[0];
    const int*   top     = (const int*)d_in[1];
    const int*   usn     = (const int*)d_in[2];
    const int*   nbid    = (const int*)d_in[3];

    int n = in_sizes[3];                                 // N_SPIKES
    int chunkA = ((n + NSLICE - 1) / NSLICE + 3) & ~3;   // mult of 4 (int4 path)
    int mb = (n + MCHUNK - 1) / MCHUNK;                  // 489 k_main blocks

    float* out        = (float*)d_out;
    float* out_cand   = out;
    float* out_counts = out + (size_t)n * T;
    float* out_scores = out_counts + (size_t)N_UNITS * N_NEIGHB;

    // Scratch in d_ws (~25.8 MB used):
    int*      wtbl = (int*)d_ws;                         // [64][400]
    int*      wne  = wtbl + N_NEIGHB * N_UNITS;          // [64]
    uint32_t* PA   = (uint32_t*)(wne + 64);              // 256*12800 = 13.1 MB
    uint32_t* PD   = PA + (size_t)NSLICE * HW_;          // 489*6400  = 12.5 MB

    k_histA  <<<NSLICE, BSA, 0, stream>>>(top, nbid, PA, n, chunkA);
    k_tables <<<N_NEIGHB, 512, 0, stream>>>(PA, usn, wtbl, wne, out_counts);
    k_main   <<<mb, BS, 0, stream>>>(logliks, top, usn, nbid, wtbl, wne,
                                     PD, out_cand, out_scores, n, MCHUNK);
    k_finalE <<<EHW / 32, BS, 0, stream>>>(PD, out_counts, mb);
}

// Round 6
// 140.863 us; speedup vs baseline: 1.0041x; 1.0041x over previous
//
#include <hip/hip_runtime.h>
#include <stdint.h>

#define N_UNITS   400
#define N_NEIGHB  64
#define C         3
#define S         2
#define T         10      // C + C*S + E, E=1
#define NSLICE    256     // kA blocks / PA slabs
#define HW_       (N_NEIGHB * N_UNITS / 2)   // 12800 packed words (4 u8 fields each)
#define NE_TOT    (N_NEIGHB * N_UNITS)       // 25600 (nb,u) entries
#define RGROUPS   8
#define SLAB_PER_G (NSLICE / RGROUPS)        // 32
#define BS        256
#define BSA       1024                        // kA block size
#define MCHUNK    2048                        // spikes per k_main block (8 tiles)
#define EHW       (N_UNITS * 16)              // 6400 u8x4-packed explore words

// ---------- JAX Threefry-2x32, key = (0, 1) (jax.random.key(1)) ----------
__device__ __forceinline__ uint32_t rotl32(uint32_t x, int d) {
    return (x << d) | (x >> (32 - d));
}

__device__ __forceinline__ void threefry_key01(uint32_t x0, uint32_t x1,
                                               uint32_t& o0, uint32_t& o1) {
    const uint32_t ks0 = 0u;
    const uint32_t ks1 = 1u;
    const uint32_t ks2 = 0x1BD11BDBu;  // 0x1BD11BDA ^ 0 ^ 1
    x0 += ks0; x1 += ks1;
#define TF_RND(r) { x0 += x1; x1 = rotl32(x1, r); x1 ^= x0; }
    TF_RND(13) TF_RND(15) TF_RND(26) TF_RND(6)
    x0 += ks1; x1 += ks2 + 1u;
    TF_RND(17) TF_RND(29) TF_RND(16) TF_RND(24)
    x0 += ks2; x1 += ks0 + 2u;
    TF_RND(13) TF_RND(15) TF_RND(26) TF_RND(6)
    x0 += ks0; x1 += ks1 + 3u;
    TF_RND(17) TF_RND(29) TF_RND(16) TF_RND(24)
    x0 += ks1; x1 += ks2 + 4u;
    TF_RND(13) TF_RND(15) TF_RND(26) TF_RND(6)
    x0 += ks2; x1 += ks0 + 5u;
#undef TF_RND
    o0 = x0; o1 = x1;
}

// jax_threefry_partitionable=True (default since jax 0.4.36):
// bits[i] = x0 ^ x1 of threefry2x32(key, (i >> 32, i & 0xffffffff)).
__device__ __forceinline__ int explore_index(int i, int ne) {
    uint32_t o0, o1;
    threefry_key01(0u, (uint32_t)i, o0, o1);
    uint32_t bits = o0 ^ o1;
    float u = __uint_as_float((bits >> 9) | 0x3F800000u) - 1.0f;
    int t = (int)floorf(u * (float)ne);
    return min(t, ne - 1);
}

// ---------- kA: single-pass full-64-nb partial histograms (u8 fields) -----
// entry e = nb*400+u; word = e>>1; lo/hi 16b half per e; within a half:
// bits 0-7 = h0 (top0 count), bits 8-15 = h12 (top1+top2 count).
// Per-slab counts are tiny (lambda ~0.3), so u8 cannot overflow.
__global__ void k_histA(const int* __restrict__ top,
                        const int* __restrict__ nbid,
                        uint32_t* __restrict__ PA, int n, int chunk) {
    __shared__ uint32_t hist[HW_];
    for (int k = threadIdx.x; k < HW_; k += blockDim.x) hist[k] = 0u;
    __syncthreads();
    int lo = blockIdx.x * chunk, hi = min(n, lo + chunk);
    const int4* top4 = (const int4*)top;
#define PROC(nb, t0, t1, t2) { \
    int b_ = (nb) * N_UNITS; \
    int e0 = b_ + (t0), e1 = b_ + (t1), e2 = b_ + (t2); \
    atomicAdd(&hist[e0 >> 1], 1u << ((e0 & 1) * 16)); \
    atomicAdd(&hist[e1 >> 1], 0x100u << ((e1 & 1) * 16)); \
    atomicAdd(&hist[e2 >> 1], 0x100u << ((e2 & 1) * 16)); }
    for (int i0 = lo + threadIdx.x * 4; i0 < hi; i0 += blockDim.x * 4) {
        if (i0 + 4 <= hi) {
            int4 nb4 = *(const int4*)(nbid + i0);
            int j = (i0 * 3) >> 2;
            int4 ta = top4[j], tb = top4[j + 1], tc = top4[j + 2];
            PROC(nb4.x, ta.x, ta.y, ta.z)
            PROC(nb4.y, ta.w, tb.x, tb.y)
            PROC(nb4.z, tb.z, tb.w, tc.x)
            PROC(nb4.w, tc.y, tc.z, tc.w)
        } else {
            for (int i = i0; i < hi; ++i)
                PROC(nbid[i], top[3 * i], top[3 * i + 1], top[3 * i + 2])
        }
    }
#undef PROC
    __syncthreads();
    uint32_t* Pb = PA + (size_t)blockIdx.x * HW_;
    for (int k = threadIdx.x; k < HW_; k += blockDim.x) Pb[k] = hist[k];
}

// ---------- kR: wide reduce of PA slabs into 8 packed partials ------------
// 400 blocks: full-chip spread of the 13.1 MB PA read (do NOT fuse into kB:
// 64-block version is latency-bound on 25% of CUs — round-4 regression).
__global__ void k_reduceA(const uint32_t* __restrict__ PA,
                          uint32_t* __restrict__ R8) {
    int idx = blockIdx.x * blockDim.x + threadIdx.x;   // 0 .. 8*HW_-1
    int w = idx % HW_;
    int g = idx / HW_;
    uint32_t h0a = 0, h12a = 0, h0b = 0, h12b = 0;
    const uint32_t* p = PA + (size_t)g * SLAB_PER_G * HW_ + w;
#pragma unroll 8
    for (int s = 0; s < SLAB_PER_G; ++s) {
        uint32_t v = p[(size_t)s * HW_];
        h0a  += v & 0xFFu;
        h12a += (v >> 8) & 0xFFu;
        h0b  += (v >> 16) & 0xFFu;
        h12b += v >> 24;
    }
    uint32_t* o = R8 + (size_t)g * NE_TOT;
    o[2 * w]     = h0a | (h12a << 16);
    o[2 * w + 1] = h0b | (h12b << 16);
}

// ---------- kB: ballot-scan tables + base counts (2 barriers) -------------
__global__ void k_tables_base(const uint32_t* __restrict__ R8,
                              const int* __restrict__ usn,
                              int* __restrict__ wtbl,
                              int* __restrict__ wne,
                              float* __restrict__ out_counts) {
    __shared__ int s_c[N_UNITS];
    __shared__ int wsum[8];
    int b = blockIdx.x;          // neighborhood id
    int u = threadIdx.x;         // 512 threads = 8 waves
    int h0 = 0, h3 = 0;
    if (u < N_UNITS) {
        int e = b * N_UNITS + u;
        // packed u16-field add: per-field totals << 65536, no cross-carry
        uint32_t tot = 0;
#pragma unroll
        for (int g = 0; g < RGROUPS; ++g) tot += R8[g * NE_TOT + e];
        h0 = (int)(tot & 0xFFFFu);
        h3 = h0 + (int)(tot >> 16);
        s_c[u] = h3;              // top0 + top1/top2 contributions
    }
    bool p = (u < N_UNITS) && (h0 > 0);
    unsigned long long m = __ballot(p);
    int lane = u & 63, wid = u >> 6;
    if (lane == 0) wsum[wid] = __popcll(m);
    int lp = __popcll(m & ((1ull << lane) - 1ull));
    __syncthreads();              // covers s_c and wsum
    int off = 0;
    for (int w2 = 0; w2 < wid; ++w2) off += wsum[w2];
    if (p) wtbl[b * N_UNITS + off + lp] = u;   // ascending unit order kept
    if (u == 0) {
        int tot = 0;
        for (int w2 = 0; w2 < 8; ++w2) tot += wsum[w2];
        wne[b] = tot;
    }
    if (u < N_UNITS && h3 > 0) {
        int2 nbr = ((const int2*)usn)[u];
        atomicAdd(&s_c[nbr.x], h3);
        atomicAdd(&s_c[nbr.y], h3);
    }
    __syncthreads();
    if (u < N_UNITS)
        out_counts[u * N_NEIGHB + b] = (float)s_c[u];
}

// ---------- k_main: pipelined, u16-staged candidates --------------------
// Per 256-spike tile t (parity p = t&1):
//   A: stage s_top[p] -> barrier -> B: dump tile t-1 (buffer 1-p), then
//   compute tile t into s_bc[p] (packed u16, -1 -> 0xFFFF).
// One barrier per tile; stores drain under the next tile's compute.
// LDS ~46.9 KB -> 3 blocks/CU (u16 staging keeps us under the 53 KB cliff).
__global__ void k_main(const float* __restrict__ logliks,
                       const int* __restrict__ top,
                       const int* __restrict__ usn,
                       const int* __restrict__ nbid,
                       const int* __restrict__ wtbl,
                       const int* __restrict__ wne,
                       uint32_t* __restrict__ PD,
                       float* __restrict__ out_cand,
                       float* __restrict__ out_scores,
                       int n, int chunk) {
    __shared__ uint32_t hist[EHW];                       // 25.6 KB
    __shared__ int   s_usn[N_UNITS * S];                 // 3.2 KB
    __shared__ float s_ll[N_UNITS];                      // 1.6 KB
    __shared__ int   s_ne[N_NEIGHB];                     // 0.25 KB
    __shared__ int   s_top[2][BS * 3];                   // 6 KB
    __shared__ alignas(16) unsigned short s_bc[2][BS * T]; // 10.24 KB
    int tid = threadIdx.x;
    for (int k = tid; k < EHW; k += BS) hist[k] = 0u;
    for (int k = tid; k < N_UNITS * S; k += BS) s_usn[k] = usn[k];
    for (int k = tid; k < N_UNITS; k += BS)     s_ll[k]  = logliks[k];
    for (int k = tid; k < N_NEIGHB; k += BS)    s_ne[k]  = wne[k];
    __syncthreads();

    int lo = blockIdx.x * chunk, hi = min(n, lo + chunk);

    // dense coalesced dump of one staged tile; scores gathered from s_ll
    auto dump = [&](int t0d, int cntd, int q) {
        int nfloat = cntd * T;
        float* oc = out_cand   + (size_t)t0d * T;
        float* os = out_scores + (size_t)t0d * T;
        const unsigned short* bc = s_bc[q];
        int nv8 = nfloat & ~7;
        for (int e = tid * 8; e < nv8; e += BS * 8) {
            uint4 w = *(const uint4*)(bc + e);
            int v0 = (short)(w.x & 0xFFFFu), v1 = (short)(w.x >> 16);
            int v2 = (short)(w.y & 0xFFFFu), v3 = (short)(w.y >> 16);
            int v4 = (short)(w.z & 0xFFFFu), v5 = (short)(w.z >> 16);
            int v6 = (short)(w.w & 0xFFFFu), v7 = (short)(w.w >> 16);
            float4 c0 = make_float4((float)v0, (float)v1, (float)v2, (float)v3);
            float4 c1 = make_float4((float)v4, (float)v5, (float)v6, (float)v7);
            float4 s0, s1;
            s0.x = (v0 >= 0) ? s_ll[v0] : 0.0f;
            s0.y = (v1 >= 0) ? s_ll[v1] : 0.0f;
            s0.z = (v2 >= 0) ? s_ll[v2] : 0.0f;
            s0.w = (v3 >= 0) ? s_ll[v3] : 0.0f;
            s1.x = (v4 >= 0) ? s_ll[v4] : 0.0f;
            s1.y = (v5 >= 0) ? s_ll[v5] : 0.0f;
            s1.z = (v6 >= 0) ? s_ll[v6] : 0.0f;
            s1.w = (v7 >= 0) ? s_ll[v7] : 0.0f;
            *(float4*)(oc + e)     = c0;
            *(float4*)(oc + e + 4) = c1;
            *(float4*)(os + e)     = s0;
            *(float4*)(os + e + 4) = s1;
        }
        for (int e = nv8 + tid; e < nfloat; e += BS) {
            int v = (short)bc[e];
            oc[e] = (float)v;
            os[e] = (v >= 0) ? s_ll[v] : 0.0f;
        }
    };

    int prev_t0 = -1, prev_cnt = 0, prev_p = 0;
    int tile = 0;
    for (int t0 = lo; t0 < hi; t0 += BS, ++tile) {
        int p = tile & 1;
        int cnt = min(BS, hi - t0);
        // A: stage this tile's top rows (t0 is 256-aligned -> int4-safe)
        if (cnt == BS) {
            if (tid < (BS * 3) / 4)
                ((int4*)s_top[p])[tid] = ((const int4*)(top + (size_t)t0 * 3))[tid];
        } else {
            for (int k = tid; k < cnt * 3; k += BS)
                s_top[p][k] = top[(size_t)t0 * 3 + k];
        }
        __syncthreads();   // s_top[p] ready; prev compute done; 2-old dump done

        // B1: dump previous tile (stores overlap the compute below)
        if (prev_t0 >= 0) dump(prev_t0, prev_cnt, prev_p);

        // B2: compute current tile into s_bc[p]
        int i = t0 + tid;
        if (i < hi) {
            int nb = nbid[i];
            int cand[T], vv[T];
            cand[0] = s_top[p][tid * 3 + 0];
            cand[1] = s_top[p][tid * 3 + 1];
            cand[2] = s_top[p][tid * 3 + 2];
#pragma unroll
            for (int c = 0; c < C; ++c) {
                cand[C + 2 * c]     = s_usn[cand[c] * 2 + 0];
                cand[C + 2 * c + 1] = s_usn[cand[c] * 2 + 1];
            }
            int ne = s_ne[nb];
            if (ne > 0) {
                int t = explore_index(i, ne);
                int ex = wtbl[nb * N_UNITS + t];
                cand[T - 1] = ex;
                // explore tail-count (pre-dup), u8 field per nb
                atomicAdd(&hist[ex * 16 + (nb >> 2)], 1u << ((nb & 3) * 8));
            } else {
                cand[T - 1] = -1;
            }
#pragma unroll
            for (int jj = 0; jj < T; ++jj) {
                bool dup = false;
#pragma unroll
                for (int k = 0; k < jj; ++k) dup |= (cand[k] == cand[jj]);
                vv[jj] = dup ? -1 : cand[jj];
            }
            // pack 10 u16 as 5 u32 LDS writes (tid*20B is 4-aligned)
            uint32_t* bw = (uint32_t*)s_bc[p] + tid * (T / 2);
#pragma unroll
            for (int k = 0; k < T / 2; ++k)
                bw[k] = (uint32_t)(unsigned short)vv[2 * k]
                      | ((uint32_t)(unsigned short)vv[2 * k + 1] << 16);
        }
        prev_t0 = t0; prev_cnt = cnt; prev_p = p;
    }
    __syncthreads();        // last tile's s_bc writes complete
    if (prev_t0 >= 0) dump(prev_t0, prev_cnt, prev_p);

    // hist atomics all completed before the barrier above
    uint32_t* Pb = PD + (size_t)blockIdx.x * EHW;
    for (int k = tid; k < EHW; k += BS) Pb[k] = hist[k];
}

// ---------- kF: reduce u8-packed explore partials into out_counts ---------
// 200 blocks: 32 words x 8 slab-groups each.
__global__ void k_finalE(const uint32_t* __restrict__ PD,
                         float* __restrict__ out_counts, int nslab) {
    __shared__ uint32_t red_e[256], red_o[256];
    int tid = threadIdx.x;
    int wl = tid & 31, g = tid >> 5;            // 8 slab groups
    int w = blockIdx.x * 32 + wl;               // word index in [0, EHW)
    int per = (nslab + 7) >> 3;
    int s0 = g * per, s1 = min(nslab, s0 + per);
    uint32_t acc_e = 0, acc_o = 0;              // u16 lanes: fields 0/2, 1/3
    for (int s = s0; s < s1; ++s) {
        uint32_t v = PD[(size_t)s * EHW + w];
        acc_e += v & 0x00FF00FFu;
        acc_o += (v >> 8) & 0x00FF00FFu;
    }
    red_e[tid] = acc_e;
    red_o[tid] = acc_o;
    __syncthreads();
    if (g == 0) {
        // unpack BEFORE combining groups (avoid u16-lane carry)
        uint32_t c0 = 0, c1 = 0, c2 = 0, c3 = 0;
#pragma unroll
        for (int k = 0; k < 8; ++k) {
            uint32_t e = red_e[wl + 32 * k], o = red_o[wl + 32 * k];
            c0 += e & 0xFFFFu;  c2 += e >> 16;
            c1 += o & 0xFFFFu;  c3 += o >> 16;
        }
        int u = w >> 4, nb4 = (w & 15) * 4;
        float4* p = (float4*)(out_counts + u * N_NEIGHB + nb4);
        float4 v = *p;
        v.x += (float)c0;
        v.y += (float)c1;
        v.z += (float)c2;
        v.w += (float)c3;
        *p = v;
    }
}

extern "C" void kernel_launch(void* const* d_in, const int* in_sizes, int n_in,
                              void* d_out, int out_size, void* d_ws, size_t ws_size,
                              hipStream_t stream) {
    const float* logliks = (const float*)d_in[0];
    const int*   top     = (const int*)d_in[1];
    const int*   usn     = (const int*)d_in[2];
    const int*   nbid    = (const int*)d_in[3];

    int n = in_sizes[3];                                 // N_SPIKES
    int chunkA = ((n + NSLICE - 1) / NSLICE + 3) & ~3;   // mult of 4 (int4 path)
    int mb = (n + MCHUNK - 1) / MCHUNK;                  // 489 k_main blocks

    float* out        = (float*)d_out;
    float* out_cand   = out;
    float* out_counts = out + (size_t)n * T;
    float* out_scores = out_counts + (size_t)N_UNITS * N_NEIGHB;

    // Scratch in d_ws (~26.6 MB used):
    int*      wtbl = (int*)d_ws;                         // [64][400]
    int*      wne  = wtbl + N_NEIGHB * N_UNITS;          // [64]
    uint32_t* R8   = (uint32_t*)(wne + 64);              // 8*25600 = 819.2 KB
    uint32_t* PA   = R8 + (size_t)RGROUPS * NE_TOT;      // 256*12800 = 13.1 MB
    uint32_t* PD   = PA + (size_t)NSLICE * HW_;          // 489*6400  = 12.5 MB

    k_histA      <<<NSLICE, BSA, 0, stream>>>(top, nbid, PA, n, chunkA);
    k_reduceA    <<<(RGROUPS * HW_) / BS, BS, 0, stream>>>(PA, R8);
    k_tables_base<<<N_NEIGHB, 512, 0, stream>>>(R8, usn, wtbl, wne, out_counts);
    k_main       <<<mb, BS, 0, stream>>>(logliks, top, usn, nbid, wtbl, wne,
                                         PD, out_cand, out_scores, n, MCHUNK);
    k_finalE     <<<EHW / 32, BS, 0, stream>>>(PD, out_counts, mb);
}